// Round 13
// baseline (162.850 us; speedup 1.0000x reference)
//
#include <hip/hip_runtime.h>
#include <hip/hip_bf16.h>
#include <stdint.h>

#define N 8192
#define E 256
#define NUM_CLASSES 100
#define MARGIN 0.1f
#define EPS 1e-4f

#define BT 64                        // Gram tile dim
#define TMT (N / BT)                 // 128 tile-rows
#define NTILES (TMT * (TMT + 1) / 2) // 8256 upper-tri tiles
#define SL (2 * TMT)                 // 256 partial slices
#define EB 256                       // fp8 row = 256 B
#define FINB 32                      // fin blocks

typedef __attribute__((ext_vector_type(4))) float floatx4;
typedef __attribute__((ext_vector_type(2))) long longx2;

struct Ctrl { double Ssum; int c2; };  // zeroed by prep block 0

// 16-lane butterfly sum on the VALU via DPP (no LDS-pipe usage).
__device__ __forceinline__ float dpp_sum16(float v) {
  v += __int_as_float(__builtin_amdgcn_update_dpp(0, __float_as_int(v), 0xB1, 0xF, 0xF, true));
  v += __int_as_float(__builtin_amdgcn_update_dpp(0, __float_as_int(v), 0x4E, 0xF, 0xF, true));
  v += __int_as_float(__builtin_amdgcn_update_dpp(0, __float_as_int(v), 0x141, 0xF, 0xF, true));
  v += __int_as_float(__builtin_amdgcn_update_dpp(0, __float_as_int(v), 0x140, 0xF, 0xF, true));
  return v;
}

// linear upper-triangle tile id -> (by, bx), bx >= by
__device__ __forceinline__ void decode_tile(int t, int& by, int& bx) {
  int y = (int)((2.0 * TMT + 1.0 -
                 __builtin_sqrt((2.0 * TMT + 1.0) * (2.0 * TMT + 1.0) - 8.0 * t)) * 0.5);
  while (y * TMT - y * (y - 1) / 2 > t) --y;
  while ((y + 1) * TMT - (y + 1) * y / 2 <= t) ++y;
  by = y;
  bx = y + (t - (y * TMT - y * (y - 1) / 2));
}

// --- Kernel 1: fp8 cast into INTERLEAVED-K layout + row norms ---------------
// Row layout: slab s (K=128 elems = 128 B) at [s*128,+128); chunk u (16 B) =
// k-bytes [u*8,+8) ++ [64+u*8,+8). A b128 read of chunk u=j*4+quad yields the
// MFMA fragments for k-steps j (low 8 B) and j+2 (high 8 B) of that slab.
// Writes contiguous; permutation applied on the read side.
__global__ __launch_bounds__(256) void prep_kernel(
    const float* __restrict__ emb, unsigned char* __restrict__ Efp8,
    float* __restrict__ sq, Ctrl* __restrict__ ctrl)
{
  const int lane = threadIdx.x & 63;
  const int wave = threadIdx.x >> 6;
  if (blockIdx.x == 0 && threadIdx.x == 0) {
    ctrl->Ssum = 0.0;
    ctrl->c2 = 0;
  }
  const int d = lane;
  const int src = (d & 32) | (((d >> 1) & 1) << 4) | (((d >> 2) & 7) << 1) | (d & 1);
  #pragma unroll
  for (int i = 0; i < 4; ++i) {
    const int row = blockIdx.x * 16 + i * 4 + wave;
    const float4 x = *(const float4*)(emb + (size_t)row * E + src * 4);
    int pk = __builtin_amdgcn_cvt_pk_fp8_f32(x.x, x.y, 0, false);
    pk = __builtin_amdgcn_cvt_pk_fp8_f32(x.z, x.w, pk, true);
    ((unsigned int*)(Efp8 + (size_t)row * EB))[d] = (unsigned int)pk;
    float s = x.x * x.x + x.y * x.y + x.z * x.z + x.w * x.w;
    #pragma unroll
    for (int off = 32; off > 0; off >>= 1) s += __shfl_down(s, off, 64);
    if (lane == 0) sq[row] = s;
  }
}

// --- Kernel 2: fp8 MFMA Gram, 64x64 tiles, direct-global, zero barriers -----
// R12 lesson: 128-tile direct-global gram is latency-bound at 2 blocks/CU
// (8.1 serial blocks x ~2x overlap). 64-tile waves carry acc[2][2] (16 AGPR)
// + ~32 frag VGPRs => ~100 regs; (256,4) caps 128 => 4 waves/SIMD, 4
// blocks/CU resident — double the overlap. Waves fully independent: no LDS,
// no __syncthreads (R11/R12); no fences (R10 lesson). Store-only doubled-
// slice epilogue (R9-R12): tile (by,bx) -> row-sums slice 2*bx+waveN segment
// by, col-sums slice 2*by+waveM segment bx; every (slice,segment) written
// exactly once -> plain stores, no init, no atomics.
__global__ __launch_bounds__(256, 4) void gram_kernel(
    const unsigned char* __restrict__ Efp8, const float* __restrict__ sq,
    const int* __restrict__ labels, float* __restrict__ numpart,
    float* __restrict__ denpart)
{
  int by, bx;
  decode_tile(blockIdx.x, by, bx);
  const bool diag = (bx == by);

  const int tid = threadIdx.x;
  const int lane = tid & 63;
  const int wave = tid >> 6;
  const int waveM = wave >> 1;
  const int waveN = wave & 1;
  const int quad = lane >> 4;
  const int l16 = lane & 15;

  const int rowBase = by * BT;
  const int colBase = bx * BT;
  const char* gbase = (const char*)Efp8;

  // 4 fragment base addresses; loads at base + s*128 + j*64
  const char* aAddr[2];
  const char* bAddr[2];
  #pragma unroll
  for (int mi = 0; mi < 2; ++mi)
    aAddr[mi] = gbase + (size_t)(rowBase + waveM * 32 + mi * 16 + l16) * EB + quad * 16;
  #pragma unroll
  for (int ni = 0; ni < 2; ++ni)
    bAddr[ni] = gbase + (size_t)(colBase + waveN * 32 + ni * 16 + l16) * EB + quad * 16;

  floatx4 acc[2][2];
  #pragma unroll
  for (int i = 0; i < 2; ++i)
    #pragma unroll
    for (int j = 0; j < 2; ++j)
      acc[i][j] = (floatx4){0.f, 0.f, 0.f, 0.f};

  #pragma unroll
  for (int s = 0; s < 2; ++s) {  // two K=128 slabs
    longx2 af[2][2], bf[2][2];   // [j][mi] b128 frags (32 VGPRs live)
    #pragma unroll
    for (int j = 0; j < 2; ++j) {
      #pragma unroll
      for (int mi = 0; mi < 2; ++mi)
        af[j][mi] = *(const longx2*)(aAddr[mi] + s * 128 + j * 64);
      #pragma unroll
      for (int ni = 0; ni < 2; ++ni)
        bf[j][ni] = *(const longx2*)(bAddr[ni] + s * 128 + j * 64);
    }
    #pragma unroll
    for (int j = 0; j < 2; ++j)
      #pragma unroll
      for (int h = 0; h < 2; ++h)  // low 8 B = step j, high 8 B = step j+2
        #pragma unroll
        for (int mi = 0; mi < 2; ++mi)
          #pragma unroll
          for (int ni = 0; ni < 2; ++ni)
            acc[mi][ni] = __builtin_amdgcn_mfma_f32_16x16x32_fp8_fp8(
                af[j][mi][h], bf[j][ni][h], acc[mi][ni], 0, 0, 0);
  }

  // ---- epilogue: registers + DPP + plain unique-writer stores --------------
  float sqc[2];
  int lc[2], cg[2];
  #pragma unroll
  for (int ni = 0; ni < 2; ++ni) {
    const int col = colBase + waveN * 32 + ni * 16 + l16;
    sqc[ni] = sq[col];
    lc[ni] = labels[col];
    cg[ni] = col;
  }

  float ncp[2] = {0.f, 0.f};
  float dcp[2] = {0.f, 0.f};

  #pragma unroll
  for (int mi = 0; mi < 2; ++mi) {
    const int rbase = rowBase + waveM * 32 + mi * 16 + quad * 4;
    const float4 sqr4 = *(const float4*)(sq + rbase);
    const int4 lr4 = *(const int4*)(labels + rbase);
    const float sqr[4] = {sqr4.x, sqr4.y, sqr4.z, sqr4.w};
    const int lr[4] = {lr4.x, lr4.y, lr4.z, lr4.w};
    float npv[4], dpv[4];
    #pragma unroll
    for (int r = 0; r < 4; ++r) {
      float np = 0.f, dp = 0.f;
      #pragma unroll
      for (int ni = 0; ni < 2; ++ni) {
        float d2 = fmaxf(fmaf(-2.f, acc[mi][ni][r], sqr[r] + sqc[ni]), EPS);
        if (diag && (rbase + r == cg[ni])) d2 = EPS;  // exact diagonal
        float d = __builtin_amdgcn_sqrtf(d2);
        float rc = __builtin_amdgcn_rcpf(d + MARGIN);
        const bool same = (lr[r] == lc[ni]);
        const float dsel = same ? d : 0.f;
        const float rsel = same ? 0.f : rc;
        np += dsel; dp += rsel;
        ncp[ni] += dsel; dcp[ni] += rsel;
      }
      npv[r] = dpp_sum16(np);
      dpv[r] = dpp_sum16(dp);
    }
    const float seln = (l16 & 2) ? ((l16 & 1) ? npv[3] : npv[2])
                                 : ((l16 & 1) ? npv[1] : npv[0]);
    const float seld = (l16 & 2) ? ((l16 & 1) ? dpv[3] : dpv[2])
                                 : ((l16 & 1) ? dpv[1] : dpv[0]);
    if ((l16 >> 2) == quad) {  // one lane per row; per-waveN slice
      const int row = rowBase + waveM * 32 + mi * 16 + l16;
      numpart[(size_t)(2 * bx + waveN) * N + row] = seln;
      denpart[(size_t)(2 * bx + waveN) * N + row] = seld;
    }
  }

  if (!diag) {  // col partials: quad-reduce in-wave, per-waveM slice
    #pragma unroll
    for (int ni = 0; ni < 2; ++ni) {
      float n2 = ncp[ni], d2 = dcp[ni];
      n2 += __shfl_xor(n2, 16, 64); d2 += __shfl_xor(d2, 16, 64);
      n2 += __shfl_xor(n2, 32, 64); d2 += __shfl_xor(d2, 32, 64);
      if (quad == 0) {
        const int col = colBase + waveN * 32 + ni * 16 + l16;
        numpart[(size_t)(2 * by + waveM) * N + col] = n2;
        denpart[(size_t)(2 * by + waveM) * N + col] = d2;
      }
    }
  }
}

// --- Kernel 3: fold 256 slices, S-reduce, last block m_sum + divide ---------
__global__ __launch_bounds__(256) void fin_kernel(
    const float* __restrict__ numpart, const float* __restrict__ denpart,
    const int* __restrict__ labels, Ctrl* __restrict__ ctrl,
    float* __restrict__ out)
{
  __shared__ double sh[4];
  __shared__ int lastflag;
  __shared__ int hist[NUM_CLASSES];
  __shared__ double shm[4];

  const int tid = threadIdx.x;
  const int lane = tid & 63;
  const int wave = tid >> 6;
  const int a = blockIdx.x * 256 + tid;

  float np = 0.f, dp = 0.f;
  #pragma unroll 8
  for (int k = 0; k < SL; ++k) {
    np += numpart[(size_t)k * N + a];
    dp += denpart[(size_t)k * N + a];
  }
  double s = (double)np * (double)dp;
  #pragma unroll
  for (int off = 32; off > 0; off >>= 1) s += __shfl_down(s, off, 64);
  if (lane == 0) sh[wave] = s;
  __syncthreads();
  if (tid == 0) {
    unsafeAtomicAdd(&ctrl->Ssum, sh[0] + sh[1] + sh[2] + sh[3]);
    __threadfence();
    const int prev = __hip_atomic_fetch_add(&ctrl->c2, 1, __ATOMIC_ACQ_REL,
                                            __HIP_MEMORY_SCOPE_AGENT);
    lastflag = (prev == FINB - 1) ? 1 : 0;
  }
  __syncthreads();

  if (lastflag) {
    if (tid < NUM_CLASSES) hist[tid] = 0;
    __syncthreads();
    for (int i = tid; i < N; i += 256) atomicAdd(&hist[labels[i]], 1);
    __syncthreads();
    double m = 0.0;
    if (tid < NUM_CLASSES) {
      const double cc = (double)hist[tid];
      m = cc * cc * (double)(N - cc);
    }
    #pragma unroll
    for (int off = 32; off > 0; off >>= 1) m += __shfl_down(m, off, 64);
    if (lane == 0) shm[wave] = m;
    __syncthreads();
    if (tid == 0) {
      const double M = shm[0] + shm[1] + shm[2] + shm[3];
      const double S = __hip_atomic_load(&ctrl->Ssum, __ATOMIC_ACQUIRE,
                                         __HIP_MEMORY_SCOPE_AGENT);
      out[0] = (float)(S / M);
    }
  }
}

extern "C" void kernel_launch(void* const* d_in, const int* in_sizes, int n_in,
                              void* d_out, int out_size, void* d_ws, size_t ws_size,
                              hipStream_t stream) {
  const float* emb = (const float*)d_in[0];
  const int* labels = (const int*)d_in[1];
  float* out = (float*)d_out;

  // ws: Efp8[2MB] | sq[32KB] | numpart[8MB] | denpart[8MB] | Ctrl  (~18 MB)
  char* w = (char*)d_ws;
  unsigned char* Efp8 = (unsigned char*)w;
  float* sq = (float*)(w + (size_t)N * EB);
  float* numpart = sq + N;
  float* denpart = numpart + (size_t)SL * N;
  Ctrl* ctrl = (Ctrl*)(denpart + (size_t)SL * N);

  prep_kernel<<<N / 16, 256, 0, stream>>>(emb, Efp8, sq, ctrl);
  gram_kernel<<<NTILES, 256, 0, stream>>>(Efp8, sq, labels, numpart, denpart);
  fin_kernel<<<FINB, 256, 0, stream>>>(numpart, denpart, labels, ctrl, out);
}

// Round 14
// 127.057 us; speedup vs baseline: 1.2817x; 1.2817x over previous
//
#include <hip/hip_runtime.h>
#include <hip/hip_bf16.h>
#include <stdint.h>

#define N 8192
#define E 256
#define NUM_CLASSES 100
#define MARGIN 0.1f
#define EPS 1e-4f

#define BT 128                      // Gram tile dim (R12 best config)
#define MT (N / BT)                 // 64 tile-rows
#define NTILES (MT * (MT + 1) / 2)  // 2080 upper-tri tiles
#define SL (2 * MT)                 // 128 partial slices
#define EB 256                      // fp8 row = 256 B
#define FINB 32                     // fin blocks

typedef __attribute__((ext_vector_type(4))) float floatx4;
typedef __attribute__((ext_vector_type(2))) long longx2;

struct Ctrl { double Ssum; int c2; };  // zeroed by prep block 0

// 16-lane butterfly sum on the VALU via DPP (no LDS-pipe usage).
__device__ __forceinline__ float dpp_sum16(float v) {
  v += __int_as_float(__builtin_amdgcn_update_dpp(0, __float_as_int(v), 0xB1, 0xF, 0xF, true));
  v += __int_as_float(__builtin_amdgcn_update_dpp(0, __float_as_int(v), 0x4E, 0xF, 0xF, true));
  v += __int_as_float(__builtin_amdgcn_update_dpp(0, __float_as_int(v), 0x141, 0xF, 0xF, true));
  v += __int_as_float(__builtin_amdgcn_update_dpp(0, __float_as_int(v), 0x140, 0xF, 0xF, true));
  return v;
}

// linear upper-triangle tile id -> (by, bx), bx >= by
__device__ __forceinline__ void decode_tile(int t, int& by, int& bx) {
  int y = (int)((2.0 * MT + 1.0 -
                 __builtin_sqrt((2.0 * MT + 1.0) * (2.0 * MT + 1.0) - 8.0 * t)) * 0.5);
  while (y * MT - y * (y - 1) / 2 > t) --y;
  while ((y + 1) * MT - (y + 1) * y / 2 <= t) ++y;
  by = y;
  bx = y + (t - (y * MT - y * (y - 1) / 2));
}

// --- Kernel 1: fp8 cast into INTERLEAVED-K layout + row norms ---------------
// Row layout: slab s (K=128 elems = 128 B) at [s*128,+128); chunk u (16 B) =
// k-bytes [u*8,+8) ++ [64+u*8,+8). A b128 read of chunk u=j*4+quad yields the
// MFMA fragments for k-steps j (low 8 B) and j+2 (high 8 B) of that slab.
__global__ __launch_bounds__(256) void prep_kernel(
    const float* __restrict__ emb, unsigned char* __restrict__ Efp8,
    float* __restrict__ sq, Ctrl* __restrict__ ctrl)
{
  const int lane = threadIdx.x & 63;
  const int wave = threadIdx.x >> 6;
  if (blockIdx.x == 0 && threadIdx.x == 0) {
    ctrl->Ssum = 0.0;
    ctrl->c2 = 0;
  }
  const int d = lane;
  const int src = (d & 32) | (((d >> 1) & 1) << 4) | (((d >> 2) & 7) << 1) | (d & 1);
  #pragma unroll
  for (int i = 0; i < 4; ++i) {
    const int row = blockIdx.x * 16 + i * 4 + wave;
    const float4 x = *(const float4*)(emb + (size_t)row * E + src * 4);
    int pk = __builtin_amdgcn_cvt_pk_fp8_f32(x.x, x.y, 0, false);
    pk = __builtin_amdgcn_cvt_pk_fp8_f32(x.z, x.w, pk, true);
    ((unsigned int*)(Efp8 + (size_t)row * EB))[d] = (unsigned int)pk;
    float s = x.x * x.x + x.y * x.y + x.z * x.z + x.w * x.w;
    #pragma unroll
    for (int off = 32; off > 0; off >>= 1) s += __shfl_down(s, off, 64);
    if (lane == 0) sq[row] = s;
  }
}

// --- Kernel 2: fp8 MFMA Gram, 128-tile, direct-global, ALL LOADS UP-FRONT ---
// R13 lesson: occupancy is not the binding constraint (65% occ ran SLOWER on
// 64-tiles: 2x L2 traffic + 2x epilogue share). R12 (this shape) was best at
// 50us but exposed load latency twice (slab s=1 loads reuse s=0 frag regs).
// Here all 32 b128 fragment loads issue up-front into distinct registers
// (128 frag VGPR + 64 acc ~= 210 total, fits (256,2)'s 256-reg cap -> no
// spill, per R9), giving one latency window + 32-deep MLP, then an
// uninterrupted 128-MFMA stream. saddr-form addressing (uniform base +
// 32-bit lane offset) trims address VGPRs. No LDS, no barriers (R11/R12),
// no fences (R10), store-only doubled-slice epilogue (R9-R13).
__global__ __launch_bounds__(256, 2) void gram_kernel(
    const unsigned char* __restrict__ Efp8, const float* __restrict__ sq,
    const int* __restrict__ labels, float* __restrict__ numpart,
    float* __restrict__ denpart)
{
  int by, bx;
  decode_tile(blockIdx.x, by, bx);
  const bool diag = (bx == by);

  const int tid = threadIdx.x;
  const int lane = tid & 63;
  const int wave = tid >> 6;
  const int waveM = wave >> 1;
  const int waveN = wave & 1;
  const int quad = lane >> 4;
  const int l16 = lane & 15;

  const int rowBase = by * BT;
  const int colBase = bx * BT;
  const unsigned char* gb = Efp8;

  // 32-bit lane offsets (saddr-form loads: uniform base + voffset)
  int offA[4], offB[4];
  #pragma unroll
  for (int mi = 0; mi < 4; ++mi)
    offA[mi] = (rowBase + waveM * 64 + mi * 16 + l16) * EB + quad * 16;
  #pragma unroll
  for (int ni = 0; ni < 4; ++ni)
    offB[ni] = (colBase + waveN * 64 + ni * 16 + l16) * EB + quad * 16;

  // all 32 fragment loads issued before any MFMA (one latency window)
  longx2 af[2][2][4], bf[2][2][4];  // [s][j][mi]: 128 VGPRs
  #pragma unroll
  for (int s = 0; s < 2; ++s)
    #pragma unroll
    for (int j = 0; j < 2; ++j) {
      #pragma unroll
      for (int mi = 0; mi < 4; ++mi)
        af[s][j][mi] = *(const longx2*)(gb + offA[mi] + s * 128 + j * 64);
      #pragma unroll
      for (int ni = 0; ni < 4; ++ni)
        bf[s][j][ni] = *(const longx2*)(gb + offB[ni] + s * 128 + j * 64);
    }

  floatx4 acc[4][4];
  #pragma unroll
  for (int i = 0; i < 4; ++i)
    #pragma unroll
    for (int j = 0; j < 4; ++j)
      acc[i][j] = (floatx4){0.f, 0.f, 0.f, 0.f};

  #pragma unroll
  for (int s = 0; s < 2; ++s)
    #pragma unroll
    for (int j = 0; j < 2; ++j)
      #pragma unroll
      for (int h = 0; h < 2; ++h)  // low 8 B = k-step j, high = j+2
        #pragma unroll
        for (int mi = 0; mi < 4; ++mi)
          #pragma unroll
          for (int ni = 0; ni < 4; ++ni)
            acc[mi][ni] = __builtin_amdgcn_mfma_f32_16x16x32_fp8_fp8(
                af[s][j][mi][h], bf[s][j][ni][h], acc[mi][ni], 0, 0, 0);

  // ---- epilogue: registers + DPP + plain unique-writer stores --------------
  float sqc[4];
  int lc[4], cg[4];
  #pragma unroll
  for (int ni = 0; ni < 4; ++ni) {
    const int col = colBase + waveN * 64 + ni * 16 + l16;
    sqc[ni] = sq[col];
    lc[ni] = labels[col];
    cg[ni] = col;
  }

  float ncp[4] = {0.f, 0.f, 0.f, 0.f};
  float dcp[4] = {0.f, 0.f, 0.f, 0.f};

  #pragma unroll
  for (int mi = 0; mi < 4; ++mi) {
    const int rbase = rowBase + waveM * 64 + mi * 16 + quad * 4;
    const float4 sqr4 = *(const float4*)(sq + rbase);
    const int4 lr4 = *(const int4*)(labels + rbase);
    const float sqr[4] = {sqr4.x, sqr4.y, sqr4.z, sqr4.w};
    const int lr[4] = {lr4.x, lr4.y, lr4.z, lr4.w};
    float npv[4], dpv[4];
    #pragma unroll
    for (int r = 0; r < 4; ++r) {
      float np = 0.f, dp = 0.f;
      #pragma unroll
      for (int ni = 0; ni < 4; ++ni) {
        float d2 = fmaxf(fmaf(-2.f, acc[mi][ni][r], sqr[r] + sqc[ni]), EPS);
        if (diag && (rbase + r == cg[ni])) d2 = EPS;  // exact diagonal
        float d = __builtin_amdgcn_sqrtf(d2);
        float rc = __builtin_amdgcn_rcpf(d + MARGIN);
        const bool same = (lr[r] == lc[ni]);
        const float dsel = same ? d : 0.f;
        const float rsel = same ? 0.f : rc;
        np += dsel; dp += rsel;
        ncp[ni] += dsel; dcp[ni] += rsel;
      }
      npv[r] = dpp_sum16(np);
      dpv[r] = dpp_sum16(dp);
    }
    const float seln = (l16 & 2) ? ((l16 & 1) ? npv[3] : npv[2])
                                 : ((l16 & 1) ? npv[1] : npv[0]);
    const float seld = (l16 & 2) ? ((l16 & 1) ? dpv[3] : dpv[2])
                                 : ((l16 & 1) ? dpv[1] : dpv[0]);
    if ((l16 >> 2) == quad) {  // one lane per row; per-waveN slice
      const int row = rowBase + waveM * 64 + mi * 16 + l16;
      numpart[(size_t)(2 * bx + waveN) * N + row] = seln;
      denpart[(size_t)(2 * bx + waveN) * N + row] = seld;
    }
  }

  if (!diag) {  // col partials: quad-reduce in-wave, per-waveM slice
    #pragma unroll
    for (int ni = 0; ni < 4; ++ni) {
      float n2 = ncp[ni], d2 = dcp[ni];
      n2 += __shfl_xor(n2, 16, 64); d2 += __shfl_xor(d2, 16, 64);
      n2 += __shfl_xor(n2, 32, 64); d2 += __shfl_xor(d2, 32, 64);
      if (quad == 0) {
        const int col = colBase + waveN * 64 + ni * 16 + l16;
        numpart[(size_t)(2 * by + waveM) * N + col] = n2;
        denpart[(size_t)(2 * by + waveM) * N + col] = d2;
      }
    }
  }
}

// --- Kernel 3: fold 128 slices, S-reduce, last block m_sum + divide ---------
__global__ __launch_bounds__(256) void fin_kernel(
    const float* __restrict__ numpart, const float* __restrict__ denpart,
    const int* __restrict__ labels, Ctrl* __restrict__ ctrl,
    float* __restrict__ out)
{
  __shared__ double sh[4];
  __shared__ int lastflag;
  __shared__ int hist[NUM_CLASSES];
  __shared__ double shm[4];

  const int tid = threadIdx.x;
  const int lane = tid & 63;
  const int wave = tid >> 6;
  const int a = blockIdx.x * 256 + tid;

  float np = 0.f, dp = 0.f;
  #pragma unroll 8
  for (int k = 0; k < SL; ++k) {
    np += numpart[(size_t)k * N + a];
    dp += denpart[(size_t)k * N + a];
  }
  double s = (double)np * (double)dp;
  #pragma unroll
  for (int off = 32; off > 0; off >>= 1) s += __shfl_down(s, off, 64);
  if (lane == 0) sh[wave] = s;
  __syncthreads();
  if (tid == 0) {
    unsafeAtomicAdd(&ctrl->Ssum, sh[0] + sh[1] + sh[2] + sh[3]);
    __threadfence();
    const int prev = __hip_atomic_fetch_add(&ctrl->c2, 1, __ATOMIC_ACQ_REL,
                                            __HIP_MEMORY_SCOPE_AGENT);
    lastflag = (prev == FINB - 1) ? 1 : 0;
  }
  __syncthreads();

  if (lastflag) {
    if (tid < NUM_CLASSES) hist[tid] = 0;
    __syncthreads();
    for (int i = tid; i < N; i += 256) atomicAdd(&hist[labels[i]], 1);
    __syncthreads();
    double m = 0.0;
    if (tid < NUM_CLASSES) {
      const double cc = (double)hist[tid];
      m = cc * cc * (double)(N - cc);
    }
    #pragma unroll
    for (int off = 32; off > 0; off >>= 1) m += __shfl_down(m, off, 64);
    if (lane == 0) shm[wave] = m;
    __syncthreads();
    if (tid == 0) {
      const double M = shm[0] + shm[1] + shm[2] + shm[3];
      const double S = __hip_atomic_load(&ctrl->Ssum, __ATOMIC_ACQUIRE,
                                         __HIP_MEMORY_SCOPE_AGENT);
      out[0] = (float)(S / M);
    }
  }
}

extern "C" void kernel_launch(void* const* d_in, const int* in_sizes, int n_in,
                              void* d_out, int out_size, void* d_ws, size_t ws_size,
                              hipStream_t stream) {
  const float* emb = (const float*)d_in[0];
  const int* labels = (const int*)d_in[1];
  float* out = (float*)d_out;

  // ws: Efp8[2MB] | sq[32KB] | numpart[4MB] | denpart[4MB] | Ctrl  (~10 MB)
  char* w = (char*)d_ws;
  unsigned char* Efp8 = (unsigned char*)w;
  float* sq = (float*)(w + (size_t)N * EB);
  float* numpart = sq + N;
  float* denpart = numpart + (size_t)SL * N;
  Ctrl* ctrl = (Ctrl*)(denpart + (size_t)SL * N);

  prep_kernel<<<N / 16, 256, 0, stream>>>(emb, Efp8, sq, ctrl);
  gram_kernel<<<NTILES, 256, 0, stream>>>(Efp8, sq, labels, numpart, denpart);
  fin_kernel<<<FINB, 256, 0, stream>>>(numpart, denpart, labels, ctrl, out);
}

// Round 15
// 111.729 us; speedup vs baseline: 1.4576x; 1.1372x over previous
//
#include <hip/hip_runtime.h>
#include <hip/hip_bf16.h>
#include <stdint.h>

#define N 8192
#define E 256
#define NUM_CLASSES 100
#define MARGIN 0.1f
#define EPS 1e-4f

#define BT 128                      // Gram tile dim
#define MT (N / BT)                 // 64 tile-rows
#define NTILES (MT * (MT + 1) / 2)  // 2080 upper-tri tiles
#define SL (2 * MT)                 // 128 partial slices
#define EB 256                      // fp8 row = 256 B
#define FINB 32                     // fin blocks

typedef __attribute__((ext_vector_type(4))) float floatx4;
typedef __attribute__((ext_vector_type(2))) long longx2;

struct Ctrl { double Ssum; int c2; };  // zeroed by prep block 0

// 16-lane butterfly sum on the VALU via DPP (no LDS-pipe usage).
__device__ __forceinline__ float dpp_sum16(float v) {
  v += __int_as_float(__builtin_amdgcn_update_dpp(0, __float_as_int(v), 0xB1, 0xF, 0xF, true));
  v += __int_as_float(__builtin_amdgcn_update_dpp(0, __float_as_int(v), 0x4E, 0xF, 0xF, true));
  v += __int_as_float(__builtin_amdgcn_update_dpp(0, __float_as_int(v), 0x141, 0xF, 0xF, true));
  v += __int_as_float(__builtin_amdgcn_update_dpp(0, __float_as_int(v), 0x140, 0xF, 0xF, true));
  return v;
}

// linear upper-triangle tile id -> (by, bx), bx >= by
__device__ __forceinline__ void decode_tile(int t, int& by, int& bx) {
  int y = (int)((2.0 * MT + 1.0 -
                 __builtin_sqrt((2.0 * MT + 1.0) * (2.0 * MT + 1.0) - 8.0 * t)) * 0.5);
  while (y * MT - y * (y - 1) / 2 > t) --y;
  while ((y + 1) * MT - (y + 1) * y / 2 <= t) ++y;
  by = y;
  bx = y + (t - (y * MT - y * (y - 1) / 2));
}

// --- Kernel 1: fp8 cast into TRANSPOSED fragment-major layout + row norms ---
// Old validated row layout (R14): row r, 16-B chunk uu (0..15) holds slab
// s=uu>>3, u=uu&7: k-bytes [s*128+u*8,+8) ++ [s*128+64+u*8,+8).
// NEW global placement (16-row-group block transpose): the 16 B that were at
// Eold[row][uu*16] now live at Etr + (row>>4)*4096 + uu*256 + (row&15)*16.
// A wave's fragment load for (s,j,mi) then covers bytes
//   group_base + (s*8+j*4)*256 + lane*16  (lane = quad*16+l16)
// = 1024 CONTIGUOUS bytes per load instruction (16 consecutive L2 lines),
// wave-uniform base + single shared voffset. Register contents are identical
// to R14's validated kernel (same row, same k-bytes per lane).
__global__ __launch_bounds__(256) void prep_kernel(
    const float* __restrict__ emb, unsigned char* __restrict__ Etr,
    float* __restrict__ sq, Ctrl* __restrict__ ctrl)
{
  const int lane = threadIdx.x & 63;
  const int wave = threadIdx.x >> 6;
  if (blockIdx.x == 0 && threadIdx.x == 0) {
    ctrl->Ssum = 0.0;
    ctrl->c2 = 0;
  }
  const int d = lane;  // dword index within the old interleaved 256-B row
  const int src = (d & 32) | (((d >> 1) & 1) << 4) | (((d >> 2) & 7) << 1) | (d & 1);
  #pragma unroll
  for (int i = 0; i < 4; ++i) {
    const int row = blockIdx.x * 16 + i * 4 + wave;
    const float4 x = *(const float4*)(emb + (size_t)row * E + src * 4);
    int pk = __builtin_amdgcn_cvt_pk_fp8_f32(x.x, x.y, 0, false);
    pk = __builtin_amdgcn_cvt_pk_fp8_f32(x.z, x.w, pk, true);
    // transposed dword index: group*1024 + uu*64 + r16*4 + (d&3)
    const int idx = ((row >> 4) << 10) + ((d >> 2) << 6) + ((row & 15) << 2) + (d & 3);
    ((unsigned int*)Etr)[idx] = (unsigned int)pk;
    float s = x.x * x.x + x.y * x.y + x.z * x.z + x.w * x.w;
    #pragma unroll
    for (int off = 32; off > 0; off >>= 1) s += __shfl_down(s, off, 64);
    if (lane == 0) sq[row] = s;
  }
}

// --- Kernel 2: fp8 MFMA Gram, 128-tile, CONTIGUOUS 1-KB fragment loads ------
// R14 lesson: up-front loads didn't help; by elimination the ~50us plateau is
// the scattered (256-B-stride) fragment loads' per-instruction line-extract
// cost. Etr makes each load 1 KB contiguous with wave-uniform base.
// No LDS, no barriers (R11/R12), no fences (R10), store-only doubled-slice
// epilogue (R9-R14), (256,2) to avoid the R9 spill cliff.
__global__ __launch_bounds__(256, 2) void gram_kernel(
    const unsigned char* __restrict__ Etr, const float* __restrict__ sq,
    const int* __restrict__ labels, float* __restrict__ numpart,
    float* __restrict__ denpart)
{
  int by, bx;
  decode_tile(blockIdx.x, by, bx);
  const bool diag = (bx == by);

  const int tid = threadIdx.x;
  const int lane = tid & 63;
  const int wave = tid >> 6;
  const int waveM = wave >> 1;
  const int waveN = wave & 1;
  const int quad = lane >> 4;
  const int l16 = lane & 15;

  const int rowBase = by * BT;
  const int colBase = bx * BT;

  // wave-uniform group bases (A: 4 row-groups, B: 4 col-groups) + shared voffset
  const unsigned char* baseA[4];
  const unsigned char* baseB[4];
  #pragma unroll
  for (int mi = 0; mi < 4; ++mi)
    baseA[mi] = Etr + ((size_t)(by * 8 + waveM * 4 + mi) << 12);
  #pragma unroll
  for (int ni = 0; ni < 4; ++ni)
    baseB[ni] = Etr + ((size_t)(bx * 8 + waveN * 4 + ni) << 12);
  const int vo = lane * 16;

  floatx4 acc[4][4];
  #pragma unroll
  for (int i = 0; i < 4; ++i)
    #pragma unroll
    for (int j = 0; j < 4; ++j)
      acc[i][j] = (floatx4){0.f, 0.f, 0.f, 0.f};

  #pragma unroll
  for (int s = 0; s < 2; ++s) {  // two K=128 slabs
    longx2 af[2][4], bf[2][4];   // [j][mi]
    #pragma unroll
    for (int j = 0; j < 2; ++j) {
      #pragma unroll
      for (int mi = 0; mi < 4; ++mi)
        af[j][mi] = *(const longx2*)(baseA[mi] + vo + (s * 8 + j * 4) * 256);
      #pragma unroll
      for (int ni = 0; ni < 4; ++ni)
        bf[j][ni] = *(const longx2*)(baseB[ni] + vo + (s * 8 + j * 4) * 256);
    }
    #pragma unroll
    for (int j = 0; j < 2; ++j)
      #pragma unroll
      for (int h = 0; h < 2; ++h)  // low 8 B = k-step j, high = j+2
        #pragma unroll
        for (int mi = 0; mi < 4; ++mi)
          #pragma unroll
          for (int ni = 0; ni < 4; ++ni)
            acc[mi][ni] = __builtin_amdgcn_mfma_f32_16x16x32_fp8_fp8(
                af[j][mi][h], bf[j][ni][h], acc[mi][ni], 0, 0, 0);
  }

  // ---- epilogue: registers + DPP + plain unique-writer stores --------------
  float sqc[4];
  int lc[4], cg[4];
  #pragma unroll
  for (int ni = 0; ni < 4; ++ni) {
    const int col = colBase + waveN * 64 + ni * 16 + l16;
    sqc[ni] = sq[col];
    lc[ni] = labels[col];
    cg[ni] = col;
  }

  float ncp[4] = {0.f, 0.f, 0.f, 0.f};
  float dcp[4] = {0.f, 0.f, 0.f, 0.f};

  #pragma unroll
  for (int mi = 0; mi < 4; ++mi) {
    const int rbase = rowBase + waveM * 64 + mi * 16 + quad * 4;
    const float4 sqr4 = *(const float4*)(sq + rbase);
    const int4 lr4 = *(const int4*)(labels + rbase);
    const float sqr[4] = {sqr4.x, sqr4.y, sqr4.z, sqr4.w};
    const int lr[4] = {lr4.x, lr4.y, lr4.z, lr4.w};
    float npv[4], dpv[4];
    #pragma unroll
    for (int r = 0; r < 4; ++r) {
      float np = 0.f, dp = 0.f;
      #pragma unroll
      for (int ni = 0; ni < 4; ++ni) {
        float d2 = fmaxf(fmaf(-2.f, acc[mi][ni][r], sqr[r] + sqc[ni]), EPS);
        if (diag && (rbase + r == cg[ni])) d2 = EPS;  // exact diagonal
        float d = __builtin_amdgcn_sqrtf(d2);
        float rc = __builtin_amdgcn_rcpf(d + MARGIN);
        const bool same = (lr[r] == lc[ni]);
        const float dsel = same ? d : 0.f;
        const float rsel = same ? 0.f : rc;
        np += dsel; dp += rsel;
        ncp[ni] += dsel; dcp[ni] += rsel;
      }
      npv[r] = dpp_sum16(np);
      dpv[r] = dpp_sum16(dp);
    }
    const float seln = (l16 & 2) ? ((l16 & 1) ? npv[3] : npv[2])
                                 : ((l16 & 1) ? npv[1] : npv[0]);
    const float seld = (l16 & 2) ? ((l16 & 1) ? dpv[3] : dpv[2])
                                 : ((l16 & 1) ? dpv[1] : dpv[0]);
    if ((l16 >> 2) == quad) {  // one lane per row; per-waveN slice
      const int row = rowBase + waveM * 64 + mi * 16 + l16;
      numpart[(size_t)(2 * bx + waveN) * N + row] = seln;
      denpart[(size_t)(2 * bx + waveN) * N + row] = seld;
    }
  }

  if (!diag) {  // col partials: quad-reduce in-wave, per-waveM slice
    #pragma unroll
    for (int ni = 0; ni < 4; ++ni) {
      float n2 = ncp[ni], d2 = dcp[ni];
      n2 += __shfl_xor(n2, 16, 64); d2 += __shfl_xor(d2, 16, 64);
      n2 += __shfl_xor(n2, 32, 64); d2 += __shfl_xor(d2, 32, 64);
      if (quad == 0) {
        const int col = colBase + waveN * 64 + ni * 16 + l16;
        numpart[(size_t)(2 * by + waveM) * N + col] = n2;
        denpart[(size_t)(2 * by + waveM) * N + col] = d2;
      }
    }
  }
}

// --- Kernel 3: fold 128 slices, S-reduce, last block m_sum + divide ---------
__global__ __launch_bounds__(256) void fin_kernel(
    const float* __restrict__ numpart, const float* __restrict__ denpart,
    const int* __restrict__ labels, Ctrl* __restrict__ ctrl,
    float* __restrict__ out)
{
  __shared__ double sh[4];
  __shared__ int lastflag;
  __shared__ int hist[NUM_CLASSES];
  __shared__ double shm[4];

  const int tid = threadIdx.x;
  const int lane = tid & 63;
  const int wave = tid >> 6;
  const int a = blockIdx.x * 256 + tid;

  float np = 0.f, dp = 0.f;
  #pragma unroll 8
  for (int k = 0; k < SL; ++k) {
    np += numpart[(size_t)k * N + a];
    dp += denpart[(size_t)k * N + a];
  }
  double s = (double)np * (double)dp;
  #pragma unroll
  for (int off = 32; off > 0; off >>= 1) s += __shfl_down(s, off, 64);
  if (lane == 0) sh[wave] = s;
  __syncthreads();
  if (tid == 0) {
    unsafeAtomicAdd(&ctrl->Ssum, sh[0] + sh[1] + sh[2] + sh[3]);
    __threadfence();
    const int prev = __hip_atomic_fetch_add(&ctrl->c2, 1, __ATOMIC_ACQ_REL,
                                            __HIP_MEMORY_SCOPE_AGENT);
    lastflag = (prev == FINB - 1) ? 1 : 0;
  }
  __syncthreads();

  if (lastflag) {
    if (tid < NUM_CLASSES) hist[tid] = 0;
    __syncthreads();
    for (int i = tid; i < N; i += 256) atomicAdd(&hist[labels[i]], 1);
    __syncthreads();
    double m = 0.0;
    if (tid < NUM_CLASSES) {
      const double cc = (double)hist[tid];
      m = cc * cc * (double)(N - cc);
    }
    #pragma unroll
    for (int off = 32; off > 0; off >>= 1) m += __shfl_down(m, off, 64);
    if (lane == 0) shm[wave] = m;
    __syncthreads();
    if (tid == 0) {
      const double M = shm[0] + shm[1] + shm[2] + shm[3];
      const double S = __hip_atomic_load(&ctrl->Ssum, __ATOMIC_ACQUIRE,
                                         __HIP_MEMORY_SCOPE_AGENT);
      out[0] = (float)(S / M);
    }
  }
}

extern "C" void kernel_launch(void* const* d_in, const int* in_sizes, int n_in,
                              void* d_out, int out_size, void* d_ws, size_t ws_size,
                              hipStream_t stream) {
  const float* emb = (const float*)d_in[0];
  const int* labels = (const int*)d_in[1];
  float* out = (float*)d_out;

  // ws: Etr[2MB] | sq[32KB] | numpart[4MB] | denpart[4MB] | Ctrl  (~10 MB)
  char* w = (char*)d_ws;
  unsigned char* Etr = (unsigned char*)w;
  float* sq = (float*)(w + (size_t)N * EB);
  float* numpart = sq + N;
  float* denpart = numpart + (size_t)SL * N;
  Ctrl* ctrl = (Ctrl*)(denpart + (size_t)SL * N);

  prep_kernel<<<N / 16, 256, 0, stream>>>(emb, Etr, sq, ctrl);
  gram_kernel<<<NTILES, 256, 0, stream>>>(Etr, sq, labels, numpart, denpart);
  fin_kernel<<<FINB, 256, 0, stream>>>(numpart, denpart, labels, ctrl, out);
}